// Round 11
// baseline (207.560 us; speedup 1.0000x reference)
//
#include <hip/hip_runtime.h>

// ---------------- problem constants ----------------
#define BATCH   8
#define LSEQ    1048576          // 1<<20
#define KCONV   500
#define TWIN    2097             // (L-K)/K + 1
#define MROWS   16776            // BATCH*TWIN
#define KDIM    4000             // KCONV * C_IN
#define NDIM    256              // 2 * C_OUT
#define COUT    128
#define VOCAB   257
#define VOCABP  256              // padding row of emb (zeros)

#define BMR     80               // m-rows per block (5 x 16)
#define NTILE   210              // ceil(MROWS/80): fits 256 CUs, 1 block/CU
#define SLABP   20               // positions per slab = 160 k = 5 BK32 iters
#define NSLAB   25
#define NG      125              // total BK32 iterations
#define PLANE   (NDIM * 32)      // 8192 shorts per g-plane of Wtf
#define AROWSH  168              // padded shorts per A-slab row (160 + 8)
#define STAGEN  (BMR * SLABP)    // 1600 gathers per slab

// ---------------- ws layout (bytes) ----------------
#define WTF_OFF   0ull
#define WTF_BYTES ((size_t)NG * PLANE * 2)                  // 2,048,000
#define POOL_OFF  (WTF_OFF + WTF_BYTES)                     // 1024 floats
#define CNT_OFF   (POOL_OFF + 4096)                         // 1 int

typedef __attribute__((ext_vector_type(8))) __bf16 bf16x8;
typedef __attribute__((ext_vector_type(4))) float  floatx4;

__device__ inline unsigned short f2bf(float f) {
    union { float f; unsigned u; } c; c.f = f;
    return (unsigned short)((c.u + 0x7FFFu + ((c.u >> 16) & 1u)) >> 16);
}
__device__ inline unsigned pack2(float lo, float hi) {
    return (unsigned)f2bf(lo) | ((unsigned)f2bf(hi) << 16);
}

// barrier that waits ONLY for LDS ops — leaves global (B/x prefetch) loads in flight
#define LDS_BARRIER() asm volatile("s_waitcnt lgkmcnt(0)\n\ts_barrier" ::: "memory")

// ---------------- kernel 1: frag-major weights + zero pool/counter ----------------
// Wtf[g][n][kk] = w_n[e=(g*32+kk)&7][p=(g*32+kk)>>3]
__global__ __launch_bounds__(256) void wprep_kernel(const float* __restrict__ w1,
                                                    const float* __restrict__ w2,
                                                    unsigned short* __restrict__ Wtf,
                                                    float* __restrict__ pool,
                                                    int* __restrict__ cnt) {
    const int n   = blockIdx.x;                        // 0..255
    const int tid = threadIdx.x;
    __shared__ float tile[KDIM];                       // 16 KB
    const float* src = (n < COUT) ? (w1 + (size_t)n * KDIM)
                                  : (w2 + (size_t)(n - COUT) * KDIM);
    for (int i = tid; i < KDIM; i += 256) tile[i] = src[i];
    __syncthreads();
    for (int i = tid; i < KDIM; i += 256) {
        int g = i >> 5, kk = i & 31;
        Wtf[(size_t)g * PLANE + n * 32 + kk] = f2bf(tile[(i & 7) * KCONV + (i >> 3)]);
    }
    if (n == 0) {
        if (tid < 256) ((float4*)pool)[tid] = float4{0.f, 0.f, 0.f, 0.f};
        if (tid == 0) *cnt = 0;
    }
}

// ---------------- kernel 2 ----------------
// ROUND 11 — C_w=64 WAVE REMAP, REGISTER-BUDGET FIXED. Pipe accounting at r10's
// 79us: LDS ~4000 cyc/slab busy (af 200 b128 = 2400 + gathers 1300 + writes
// 300) vs MFMA 1940, L1-B 1250 -> LDS is the serving-rate limiter. The only
// structural cut is fewer af re-reads per row: 8 waves = 4 col-groups x 2
// row-groups (rows 48/32 via template). af/slab 200 -> 100 (LDS ~2800); B-frag
// read by 2 waves (L1-cached, L1 1250 -> 2500); pipes balanced. r1 tested this
// remap but with VGPR capped at 84 (default launch_bounds) which collapsed the
// B depth-2 pipeline — and was STILL cross-session neutral (88.6 vs r4's 87.5).
// Fix: __launch_bounds__(512, 2) = 2 waves/SIMD (exactly our 1-block/CU
// occupancy) -> 256 VGPR budget; acc(48)+B(48)+af(12)+gr(16)+misc ~ 155, no
// spill (tripwire: WRITE_SIZE must stay ~1MB; r9's spill showed 8.3MB).
// Retained from r10: staggered staging (gather-read at kt under MFMAs, write
// at kt+1; lgkm in-order makes both free), 16B table entries (single b128
// gather), compute-first ordering, lgkm-only barrier, x prefetch a slab
// ahead, fused head with relaxed device-scope sync.
template<int ROWT, int RBASE>
__device__ __forceinline__ void gemm_path(
    const unsigned short* __restrict__ Wtf,
    const float* __restrict__ b1, const float* __restrict__ b2,
    float* __restrict__ pool,
    unsigned short* AsBase, const unsigned short* tableL,
    const int* const (&xptr)[4], const int (&loff)[4], const bool (&sval)[4],
    const bool (&sact)[4], int tid, int m0)
{
    const int lane = tid & 63;
    const int r16  = lane & 15;
    const int q    = lane >> 4;                        // 0..3
    const int cg   = (tid >> 6) & 3;                   // col-group 0..3

    const int o0 = cg * 32 + r16;                      // first owned column
    const int o1 = o0 + 16;                            // second owned column

    const size_t boff[4] = {
        (size_t)o0 * 32 + q * 8,
        (size_t)(o0 + 128) * 32 + q * 8,
        (size_t)o1 * 32 + q * 8,
        (size_t)(o1 + 128) * 32 + q * 8
    };

    floatx4 acc[ROWT][4];
#pragma unroll
    for (int i = 0; i < ROWT; ++i)
#pragma unroll
        for (int j = 0; j < 4; ++j) acc[i][j] = floatx4{0, 0, 0, 0};

    // ---- x values for slab 0 ----
    int xv[4], xn[4];
#pragma unroll
    for (int l = 0; l < 4; ++l) xv[l] = sval[l] ? xptr[l][0] : VOCABP;
    __syncthreads();                                   // table visible

    // ---- stage slab 0 into buf 0 (unavoidable burst before first compute) ----
#pragma unroll
    for (int l = 0; l < 4; ++l) {
        if (sact[l]) {
            uint4 g = *(const uint4*)(tableL + xv[l] * 8);
            *(uint4*)(AsBase + loff[l]) = g;
        }
    }
#pragma unroll
    for (int l = 0; l < 4; ++l) xv[l] = sval[l] ? xptr[l][SLABP] : VOCABP;
    LDS_BARRIER();

    // ---- B prefetch prologue: g=0,1 (4 frags x 2 stages) ----
    bf16x8 bc0[4], bc1[4], bc2[4] = {};
#pragma unroll
    for (int j = 0; j < 4; ++j) {
        bc0[j] = *(const bf16x8*)(Wtf + boff[j]);
        bc1[j] = *(const bf16x8*)(Wtf + PLANE + boff[j]);
    }

    int buf = 0;
    for (int s = 0; s < NSLAB; ++s) {
        if (s + 2 < NSLAB) {
#pragma unroll
            for (int l = 0; l < 4; ++l)
                xn[l] = sval[l] ? xptr[l][(s + 2) * SLABP] : VOCABP;
        }

        const unsigned short* Asb  = AsBase + buf * (BMR * AROWSH);
        unsigned short*       dstS = AsBase + (buf ^ 1) * (BMR * AROWSH);
        const bool stg = (s + 1 < NSLAB);
        uint4 gr[4];

        // ---- 5 BK=32 iterations; B depth-2 pipeline; staggered staging ----
#pragma unroll
        for (int kt = 0; kt < 5; ++kt) {
            const int g = s * 5 + kt;
            if (g + 2 < NG) {
                const unsigned short* Wp = Wtf + (size_t)(g + 2) * PLANE;
#pragma unroll
                for (int j = 0; j < 4; ++j)
                    bc2[j] = *(const bf16x8*)(Wp + boff[j]);
            }
            bf16x8 af[ROWT];
#pragma unroll
            for (int i = 0; i < ROWT; ++i)
                af[i] = *(const bf16x8*)(Asb + ((RBASE + i) * 16 + r16) * AROWSH
                                         + (kt * 4 + q) * 8);

            // gather-READ slot kt: single b128; issued with this kt's af reads
            if (kt < 4 && stg && sact[kt])
                gr[kt] = *(const uint4*)(tableL + xv[kt] * 8);

#pragma unroll
            for (int i = 0; i < ROWT; ++i) {
#pragma unroll
                for (int j = 0; j < 4; ++j)
                    acc[i][j] = __builtin_amdgcn_mfma_f32_16x16x32_bf16(
                        af[i], bc0[j], acc[i][j], 0, 0, 0);
            }
#pragma unroll
            for (int j = 0; j < 4; ++j) { bc0[j] = bc1[j]; bc1[j] = bc2[j]; }

            // gather-WRITE slot kt-1: data arrived a full kt ago -> no stall
            if (kt >= 1 && stg && sact[kt - 1])
                *(uint4*)(dstS + loff[kt - 1]) = gr[kt - 1];
        }
#pragma unroll
        for (int l = 0; l < 4; ++l) xv[l] = xn[l];
        LDS_BARRIER();
        buf ^= 1;
    }

    // ---- epilogue: gate + per-batch max, two columns per lane ----
    // C/D layout: col = lane&15 (n), row = q*4 + reg (m).
    const float b10 = b1[o0], b20 = b2[o0];
    const float b11 = b1[o1], b21 = b2[o1];
    float cur0 = 0.0f, cur1 = 0.0f;
    int curb = (m0 + RBASE * 16 + q * 4) / TWIN;
#pragma unroll
    for (int i = 0; i < ROWT; ++i) {
#pragma unroll
        for (int rg = 0; rg < 4; ++rg) {
            const int row = m0 + (RBASE + i) * 16 + q * 4 + rg;
            if (row < MROWS) {
                const int bb = row / TWIN;
                if (bb != curb) {
                    atomicMax((int*)&pool[curb * COUT + o0], __float_as_int(cur0));
                    atomicMax((int*)&pool[curb * COUT + o1], __float_as_int(cur1));
                    cur0 = 0.0f; cur1 = 0.0f; curb = bb;
                }
                {
                    const float c1 = acc[i][0][rg] + b10;
                    const float c2 = acc[i][1][rg] + b20;
                    cur0 = fmaxf(cur0, fmaxf(c1, 0.0f) / (1.0f + __expf(-c2)));
                }
                {
                    const float c1 = acc[i][2][rg] + b11;
                    const float c2 = acc[i][3][rg] + b21;
                    cur1 = fmaxf(cur1, fmaxf(c1, 0.0f) / (1.0f + __expf(-c2)));
                }
            }
        }
    }
    atomicMax((int*)&pool[curb * COUT + o0], __float_as_int(cur0));
    atomicMax((int*)&pool[curb * COUT + o1], __float_as_int(cur1));
}

__global__ __launch_bounds__(512, 2) void gemm_kernel(const int* __restrict__ x,
                                                      const float* __restrict__ emb,
                                                      const unsigned short* __restrict__ Wtf,
                                                      const float* __restrict__ b1,
                                                      const float* __restrict__ b2,
                                                      float* __restrict__ pool,
                                                      int* __restrict__ cnt,
                                                      const float* __restrict__ wd1,
                                                      const float* __restrict__ bd1,
                                                      const float* __restrict__ wd2,
                                                      const float* __restrict__ bd2,
                                                      float* __restrict__ out) {
    __shared__ __align__(16) unsigned short tableL[VOCAB * 8];   // 4112 B
    __shared__ __align__(16) unsigned short As[2][BMR * AROWSH]; // 2 x 26.25 KB

    const int tid = threadIdx.x;
    const int m0  = blockIdx.x * BMR;

    // ---- build bf16 emb table in LDS (16B entries) ----
    if (tid < VOCAB) {
        const float4* er = (const float4*)(emb + tid * 8);
        float4 a = er[0], b = er[1];
        uint4 u;
        u.x = pack2(a.x, a.y); u.y = pack2(a.z, a.w);
        u.z = pack2(b.x, b.y); u.w = pack2(b.z, b.w);
        *(uint4*)(tableL + tid * 8) = u;
    }

    // ---- staging roles: thread handles idx = tid + 512*l (idx < 1600) ----
    const int* xptr[4];
    int        loff[4];
    bool       sval[4];
    bool       sact[4];
#pragma unroll
    for (int l = 0; l < 4; ++l) {
        sact[l] = (l < 3) || (tid < STAGEN - 3 * 512);
        int idx = tid + 512 * l;
        sval[l] = (idx < STAGEN);
        int ic  = sval[l] ? idx : 0;
        int row = ic / SLABP;
        int pos = ic - row * SLABP;
        int am  = m0 + row;
        bool av = sval[l] && (am < MROWS);
        sval[l] = av;
        int amc = av ? am : 0;
        int b   = amc / TWIN;
        int t   = amc - b * TWIN;
        xptr[l] = x + ((size_t)b * LSEQ + (size_t)t * KCONV + pos);
        loff[l] = row * AROWSH + pos * 8;
    }

    // row-group split 48/32: waves 0-3 take row tiles 0-2, waves 4-7 tiles 3-4.
    // Both paths execute identical barrier sequences (verified structure, r1).
    if (tid < 256)
        gemm_path<3, 0>(Wtf, b1, b2, pool, (unsigned short*)As, tableL,
                        xptr, loff, sval, sact, tid, m0);
    else
        gemm_path<2, 3>(Wtf, b1, b2, pool, (unsigned short*)As, tableL,
                        xptr, loff, sval, sact, tid, m0);

    // ---- fused head: last block to finish does the dense layers ----
    asm volatile("s_waitcnt vmcnt(0)" ::: "memory");
    __syncthreads();
    __shared__ int lastFlag;
    if (tid == 0) {
        int prev = __hip_atomic_fetch_add(cnt, 1, __ATOMIC_RELAXED, __HIP_MEMORY_SCOPE_AGENT);
        lastFlag = (prev == NTILE - 1) ? 1 : 0;
    }
    __syncthreads();
    if (!lastFlag) return;

    // reuse As as scratch: poolL[1024] + red[8][128]
    float* poolL = (float*)As;
    float* red   = poolL + BATCH * COUT;
    poolL[tid] = __int_as_float(
        __hip_atomic_load((int*)&pool[tid], __ATOMIC_RELAXED, __HIP_MEMORY_SCOPE_AGENT));
    poolL[tid + 512] = __int_as_float(
        __hip_atomic_load((int*)&pool[tid + 512], __ATOMIC_RELAXED, __HIP_MEMORY_SCOPE_AGENT));
    __syncthreads();

    if (tid < COUT) {
        const int j = tid;
        const float wj = wd2[j];
#pragma unroll
        for (int b = 0; b < BATCH; ++b) {
            float s = bd1[j];
            for (int i = 0; i < COUT; ++i) s += poolL[b * COUT + i] * wd1[j * COUT + i];
            red[b * COUT + j] = fmaxf(s, 0.0f) * wj;
        }
    }
    __syncthreads();
    if (tid < BATCH) {
        float s = 0.0f;
        for (int i = 0; i < COUT; ++i) s += red[tid * COUT + i];
        out[tid] = 1.0f / (1.0f + expf(-(s + bd2[0])));
    }
}

// ---------------- launch ----------------
extern "C" void kernel_launch(void* const* d_in, const int* in_sizes, int n_in,
                              void* d_out, int out_size, void* d_ws, size_t ws_size,
                              hipStream_t stream) {
    const int*   x   = (const int*)d_in[0];
    const float* emb = (const float*)d_in[1];
    const float* w1  = (const float*)d_in[2];
    const float* b1  = (const float*)d_in[3];
    const float* w2  = (const float*)d_in[4];
    const float* b2  = (const float*)d_in[5];
    const float* wd1 = (const float*)d_in[6];
    const float* bd1 = (const float*)d_in[7];
    const float* wd2 = (const float*)d_in[8];
    const float* bd2 = (const float*)d_in[9];
    float* out = (float*)d_out;

    unsigned short* Wtf  = (unsigned short*)((char*)d_ws + WTF_OFF);
    float*          pool = (float*)((char*)d_ws + POOL_OFF);
    int*            cnt  = (int*)((char*)d_ws + CNT_OFF);

    wprep_kernel<<<dim3(NDIM), dim3(256), 0, stream>>>(w1, w2, Wtf, pool, cnt);
    gemm_kernel<<<dim3(NTILE), dim3(512), 0, stream>>>(x, emb, Wtf, b1, b2, pool, cnt,
                                                       wd1, bd1, wd2, bd2, out);
}